// Round 7
// baseline (221.889 us; speedup 1.0000x reference)
//
#include <hip/hip_runtime.h>

#define DIM 512
#define NHEAD 8
#define HDIM 64
#define BATCH 4
#define SEQ 2048
#define MTOT (BATCH*SEQ)
#define SCALE 0.125f
#define LOG2E 1.4426950408889634f

typedef __bf16 bf16_t;
typedef __bf16 bf16x8 __attribute__((ext_vector_type(8)));
typedef __bf16 bf16x4 __attribute__((ext_vector_type(4)));
typedef float f32x4 __attribute__((ext_vector_type(4)));

#define ASYNC_COPY16(g, l) __builtin_amdgcn_global_load_lds( \
    (const __attribute__((address_space(1))) void*)(g),      \
    (__attribute__((address_space(3))) void*)(l), 16, 0, 0)

// ---------------- fused fp32 -> bf16 convert (x | w_qkv | w_proj) ----------------
#define NX_ELEM  (4194304)
#define NWQ_ELEM (786432)
#define NWP_ELEM (262144)
__global__ __launch_bounds__(256) void cvt_kernel(const float* __restrict__ x,
                                                  const float* __restrict__ wq,
                                                  const float* __restrict__ wp,
                                                  bf16_t* __restrict__ out) {
    int i = (blockIdx.x * 256 + threadIdx.x) * 4;
    const float* src;
    if (i < NX_ELEM)                 src = x  + i;
    else if (i < NX_ELEM + NWQ_ELEM) src = wq + (i - NX_ELEM);
    else                             src = wp + (i - NX_ELEM - NWQ_ELEM);
    float4 v = *reinterpret_cast<const float4*>(src);
    bf16x4 o;
    o[0] = (bf16_t)v.x; o[1] = (bf16_t)v.y; o[2] = (bf16_t)v.z; o[3] = (bf16_t)v.w;
    *reinterpret_cast<bf16x4*>(out + i) = o;
}

// ---------------- QKV GEMM: m97 structure (global_load_lds w16, linear LDS) ----------------
__global__ __launch_bounds__(256) void gemm_qkv_kernel(
    const bf16_t* __restrict__ X, const bf16_t* __restrict__ W,
    const float* __restrict__ bias,
    bf16_t* __restrict__ Qo, bf16_t* __restrict__ Ko, bf16_t* __restrict__ Vto)
{
    __shared__ bf16_t As[128][64];
    __shared__ bf16_t Bs[128][64];
    const int tid = threadIdx.x;
    const int wave = tid >> 6, lane = tid & 63;
    const int lhi = lane >> 4, llo = lane & 15;
    const int o = blockIdx.x;
    const int x = o & 7, i0 = o >> 3;
    const int m0 = (x * 8 + (i0 & 7)) * 128;
    const int n0 = (i0 >> 3) * 128;
    const int wr = (wave >> 1) * 64, wc = (wave & 1) * 64;
    f32x4 acc[4][4] = {};

    const int srow = wave * 32 + (lane >> 3);
    const int scol = (lane & 7) * 8;
    const bf16_t* gA = X + (size_t)(m0 + srow) * DIM + scol;
    const bf16_t* gB = W + (size_t)(n0 + srow) * DIM + scol;

    for (int k0 = 0; k0 < DIM; k0 += 64) {
        #pragma unroll
        for (int p = 0; p < 4; ++p) {
            ASYNC_COPY16(gA + (size_t)p * 8 * DIM + k0, &As[wave*32 + p*8][0]);
            ASYNC_COPY16(gB + (size_t)p * 8 * DIM + k0, &Bs[wave*32 + p*8][0]);
        }
        __syncthreads();
        #pragma unroll
        for (int ks = 0; ks < 2; ++ks) {
            bf16x8 af[4], bfr[4];
            #pragma unroll
            for (int i = 0; i < 4; ++i)
                af[i] = *reinterpret_cast<const bf16x8*>(&As[wr + i*16 + llo][ks*32 + lhi*8]);
            #pragma unroll
            for (int j = 0; j < 4; ++j)
                bfr[j] = *reinterpret_cast<const bf16x8*>(&Bs[wc + j*16 + llo][ks*32 + lhi*8]);
            __builtin_amdgcn_s_setprio(1);
            #pragma unroll
            for (int i = 0; i < 4; ++i)
                #pragma unroll
                for (int j = 0; j < 4; ++j)
                    acc[i][j] = __builtin_amdgcn_mfma_f32_16x16x32_bf16(af[i], bfr[j], acc[i][j], 0, 0, 0);
            __builtin_amdgcn_s_setprio(0);
        }
        __syncthreads();
    }

    #pragma unroll
    for (int j = 0; j < 4; ++j) {
        int col = n0 + wc + j*16 + llo;
        int which = col >> 9;
        int hh = (col >> 6) & 7;
        int dd = col & 63;
        float bv = bias[col];
        #pragma unroll
        for (int i = 0; i < 4; ++i) {
            #pragma unroll
            for (int r = 0; r < 4; ++r) {
                int m = m0 + wr + i*16 + lhi*4 + r;
                int b = m >> 11, ns = m & 2047;
                float v = acc[i][j][r] + bv;
                size_t bh = (size_t)(b * NHEAD + hh);
                if (which == 0)
                    Qo[(bh * SEQ + ns) * HDIM + dd] = (bf16_t)(v * (SCALE * LOG2E));
                else if (which == 1)
                    Ko[(bh * SEQ + ns) * HDIM + dd] = (bf16_t)v;
                else
                    Vto[(bh * HDIM + dd) * SEQ + ns] = (bf16_t)v;
            }
        }
    }
}

// ---------------- Flash attention v7: NO LDS, NO BARRIERS ----------------
// K/V per bh = 256KB each -> L2-resident (4 bh/XCD = 2MB). All 4 waves of a
// block read IDENTICAL frag addresses -> L1 serves ~3/4 of reads. Each wave
// free-runs: K-frags + V-frags loaded straight from global in MFMA fragment
// layout. Swapped QK^T, lane-local softmax, defer-max, reg-packed PV.
__global__ __launch_bounds__(256, 2) void attn_kernel(
    const bf16_t* __restrict__ Q, const bf16_t* __restrict__ K,
    const bf16_t* __restrict__ Vt, bf16_t* __restrict__ O)
{
    const int tid = threadIdx.x;
    const int wave = tid >> 6, lane = tid & 63;
    const int lhi = lane >> 4, llo = lane & 15;
    // XCD swizzle: 512 blocks, 64/XCD -> 4 complete bh per XCD (K/V L2-resident)
    const int o = blockIdx.x;
    const int w = (o & 7) * 64 + (o >> 3);
    const int qt = w & 15, bh = w >> 4;
    const bf16_t* Qb = Q + (size_t)bh * SEQ * HDIM;
    const bf16_t* Kb = K + (size_t)bh * SEQ * HDIM;
    const bf16_t* Vb = Vt + (size_t)bh * HDIM * SEQ;
    const int q0 = qt * 128 + wave * 32;

    // Q fragments (pre-scaled by SCALE*log2e); B-frag: col=llo=q, k=lhi*8+j
    bf16x8 aq[2][2];
    #pragma unroll
    for (int qb = 0; qb < 2; ++qb)
        #pragma unroll
        for (int ks = 0; ks < 2; ++ks)
            aq[qb][ks] = *reinterpret_cast<const bf16x8*>(
                Qb + (size_t)(q0 + qb*16 + llo) * HDIM + ks*32 + lhi*8);

    f32x4 acc_o[2][4] = {};          // [qb][db]: q=qb*16+lhi*4+r, d=db*16+llo
    float mstat[2], lstat[2];
    mstat[0] = mstat[1] = -1e30f;
    lstat[0] = lstat[1] = 0.f;
    const float THR = 8.0f * LOG2E;

    // K-frag base: key = kb*16 + llo, d = ks*32 + lhi*8
    const bf16_t* kbase = Kb + (size_t)llo * HDIM + lhi * 8;
    // V-frag base: d = db*16 + llo, key = koff + kp*32 + c*16 + lhi*4
    const bf16_t* vbase = Vb + (size_t)llo * SEQ + lhi * 4;

    // prologue: K-frags for tile 0
    bf16x8 kf[4][2];
    #pragma unroll
    for (int kb = 0; kb < 4; ++kb)
        #pragma unroll
        for (int ks = 0; ks < 2; ++ks)
            kf[kb][ks] = *reinterpret_cast<const bf16x8*>(
                kbase + (size_t)(kb*16) * HDIM + ks*32);

    const int NT = SEQ / 64;
    for (int kt = 0; kt < NT; ++kt) {
        const int koff = kt * 64;

        // V-frag loads for this tile (used ~700cyc later at PV)
        uint2 vf[2][4][2];
        #pragma unroll
        for (int kp = 0; kp < 2; ++kp)
            #pragma unroll
            for (int db = 0; db < 4; ++db)
                #pragma unroll
                for (int c = 0; c < 2; ++c)
                    vf[kp][db][c] = *reinterpret_cast<const uint2*>(
                        vbase + (size_t)(db*16) * SEQ + koff + kp*32 + c*16);

        // S^T = K Q^T: s[qb][kb], key=kb*16+lhi*4+r, q=llo
        f32x4 s[2][4] = {};
        __builtin_amdgcn_s_setprio(1);
        #pragma unroll
        for (int kb = 0; kb < 4; ++kb)
            #pragma unroll
            for (int ks = 0; ks < 2; ++ks)
                #pragma unroll
                for (int qb = 0; qb < 2; ++qb)
                    s[qb][kb] = __builtin_amdgcn_mfma_f32_16x16x32_bf16(kf[kb][ks], aq[qb][ks], s[qb][kb], 0, 0, 0);
        __builtin_amdgcn_s_setprio(0);

        // prefetch K-frags for next tile (lands during softmax+PV)
        if (kt + 1 < NT) {
            #pragma unroll
            for (int kb = 0; kb < 4; ++kb)
                #pragma unroll
                for (int ks = 0; ks < 2; ++ks)
                    kf[kb][ks] = *reinterpret_cast<const bf16x8*>(
                        kbase + (size_t)(koff + 64 + kb*16) * HDIM + ks*32);
        }

        // defer-max over lane-local 16 keys per qb
        float lmax[2];
        bool ok = true;
        #pragma unroll
        for (int qb = 0; qb < 2; ++qb) {
            float mx = s[qb][0][0];
            #pragma unroll
            for (int kb = 0; kb < 4; ++kb)
                #pragma unroll
                for (int r = 0; r < 4; ++r) mx = fmaxf(mx, s[qb][kb][r]);
            lmax[qb] = mx;
            ok &= (mx <= mstat[qb] + THR);
        }

        if (!__all(ok)) {
            #pragma unroll
            for (int qb = 0; qb < 2; ++qb) {
                float mx = lmax[qb];
                mx = fmaxf(mx, __shfl_xor(mx, 16, 64));
                mx = fmaxf(mx, __shfl_xor(mx, 32, 64));
                float mold = mstat[qb];
                float mn = fmaxf(mold, mx);
                float alpha = __builtin_amdgcn_exp2f(mold - mn);
                mstat[qb] = mn;
                lstat[qb] *= alpha;
                #pragma unroll
                for (int r = 0; r < 4; ++r) {
                    float av = __shfl(alpha, (lane & 48) >> 2 | r, 64);
                    #pragma unroll
                    for (int db = 0; db < 4; ++db) acc_o[qb][db][r] *= av;
                }
            }
        }

        // P = exp2(s - m); lane-local row-sum + 2 shfl_xor
        #pragma unroll
        for (int qb = 0; qb < 2; ++qb) {
            float rs = 0.f;
            #pragma unroll
            for (int kb = 0; kb < 4; ++kb)
                #pragma unroll
                for (int r = 0; r < 4; ++r) {
                    float pv = __builtin_amdgcn_exp2f(s[qb][kb][r] - mstat[qb]);
                    s[qb][kb][r] = pv;
                    rs += pv;
                }
            rs += __shfl_xor(rs, 16, 64);
            rs += __shfl_xor(rs, 32, 64);
            lstat[qb] += rs;
        }

        // pack P into A-frags + PV from register V-frags
        #pragma unroll
        for (int kp = 0; kp < 2; ++kp) {
            bf16x8 ap[2];
            #pragma unroll
            for (int qb = 0; qb < 2; ++qb)
                #pragma unroll
                for (int j = 0; j < 4; ++j) {
                    ap[qb][j]     = (bf16_t)s[qb][2*kp][j];
                    ap[qb][4 + j] = (bf16_t)s[qb][2*kp + 1][j];
                }
            __builtin_amdgcn_s_setprio(1);
            #pragma unroll
            for (int db = 0; db < 4; ++db) {
                bf16x4 l0 = *reinterpret_cast<const bf16x4*>(&vf[kp][db][0]);
                bf16x4 l1 = *reinterpret_cast<const bf16x4*>(&vf[kp][db][1]);
                bf16x8 bv;
                #pragma unroll
                for (int j = 0; j < 4; ++j) { bv[j] = l0[j]; bv[4 + j] = l1[j]; }
                #pragma unroll
                for (int qb = 0; qb < 2; ++qb)
                    acc_o[qb][db] = __builtin_amdgcn_mfma_f32_16x16x32_bf16(ap[qb], bv, acc_o[qb][db], 0, 0, 0);
            }
            __builtin_amdgcn_s_setprio(0);
        }
    }

    // normalize (stats at q=llo lanes; acc at q=lhi*4+r) + write [B,N,H*64]
    const int b = bh >> 3, h = bh & 7;
    #pragma unroll
    for (int qb = 0; qb < 2; ++qb) {
        float inv = 1.0f / lstat[qb];
        #pragma unroll
        for (int r = 0; r < 4; ++r) {
            float iv = __shfl(inv, (lane & 48) >> 2 | r, 64);
            int q = q0 + qb*16 + lhi*4 + r;
            #pragma unroll
            for (int db = 0; db < 4; ++db)
                O[(size_t)(b * SEQ + q) * DIM + h*HDIM + db*16 + llo] =
                    (bf16_t)(acc_o[qb][db][r] * iv);
        }
    }
}

// ---------------- Output proj GEMM: m97 structure ----------------
__global__ __launch_bounds__(256) void gemm_proj_kernel(
    const bf16_t* __restrict__ X, const bf16_t* __restrict__ W,
    const float* __restrict__ bias, float* __restrict__ out)
{
    __shared__ bf16_t As[128][64];
    __shared__ bf16_t Bs[128][64];
    const int tid = threadIdx.x;
    const int wave = tid >> 6, lane = tid & 63;
    const int lhi = lane >> 4, llo = lane & 15;
    const int o = blockIdx.x;
    const int x = o & 7, i0 = o >> 3;
    const int m0 = (x * 8 + (i0 & 7)) * 128;
    const int n0 = (i0 >> 3) * 128;
    const int wr = (wave >> 1) * 64, wc = (wave & 1) * 64;
    f32x4 acc[4][4] = {};

    const int srow = wave * 32 + (lane >> 3);
    const int scol = (lane & 7) * 8;
    const bf16_t* gA = X + (size_t)(m0 + srow) * DIM + scol;
    const bf16_t* gB = W + (size_t)(n0 + srow) * DIM + scol;

    for (int k0 = 0; k0 < DIM; k0 += 64) {
        #pragma unroll
        for (int p = 0; p < 4; ++p) {
            ASYNC_COPY16(gA + (size_t)p * 8 * DIM + k0, &As[wave*32 + p*8][0]);
            ASYNC_COPY16(gB + (size_t)p * 8 * DIM + k0, &Bs[wave*32 + p*8][0]);
        }
        __syncthreads();
        #pragma unroll
        for (int ks = 0; ks < 2; ++ks) {
            bf16x8 af[4], bfr[4];
            #pragma unroll
            for (int i = 0; i < 4; ++i)
                af[i] = *reinterpret_cast<const bf16x8*>(&As[wr + i*16 + llo][ks*32 + lhi*8]);
            #pragma unroll
            for (int j = 0; j < 4; ++j)
                bfr[j] = *reinterpret_cast<const bf16x8*>(&Bs[wc + j*16 + llo][ks*32 + lhi*8]);
            __builtin_amdgcn_s_setprio(1);
            #pragma unroll
            for (int i = 0; i < 4; ++i)
                #pragma unroll
                for (int j = 0; j < 4; ++j)
                    acc[i][j] = __builtin_amdgcn_mfma_f32_16x16x32_bf16(af[i], bfr[j], acc[i][j], 0, 0, 0);
            __builtin_amdgcn_s_setprio(0);
        }
        __syncthreads();
    }

    #pragma unroll
    for (int j = 0; j < 4; ++j) {
        int col = n0 + wc + j*16 + llo;
        float bv = bias[col];
        #pragma unroll
        for (int i = 0; i < 4; ++i)
            #pragma unroll
            for (int r = 0; r < 4; ++r) {
                int m = m0 + wr + i*16 + lhi*4 + r;
                out[(size_t)m * DIM + col] = acc[i][j][r] + bv;
            }
    }
}

extern "C" void kernel_launch(void* const* d_in, const int* in_sizes, int n_in,
                              void* d_out, int out_size, void* d_ws, size_t ws_size,
                              hipStream_t stream) {
    const float* x      = (const float*)d_in[0];
    const float* w_qkv  = (const float*)d_in[1];
    const float* b_qkv  = (const float*)d_in[2];
    const float* w_proj = (const float*)d_in[3];
    const float* b_proj = (const float*)d_in[4];
    float* out = (float*)d_out;

    const size_t NX  = (size_t)MTOT * DIM;
    const size_t NWQ = (size_t)3 * DIM * DIM;
    const size_t NWP = (size_t)DIM * DIM;
    const size_t NQ  = (size_t)BATCH * NHEAD * SEQ * HDIM;

    bf16_t* Xb    = (bf16_t*)d_ws;
    bf16_t* Wqkv  = Xb + NX;
    bf16_t* Wproj = Wqkv + NWQ;
    bf16_t* Qb    = Wproj + NWP;
    bf16_t* Kb    = Qb + NQ;
    bf16_t* Vtb   = Kb + NQ;
    bf16_t* AOb   = Vtb + NQ;

    cvt_kernel<<<(int)((NX + NWQ + NWP) / 1024), 256, 0, stream>>>(x, w_qkv, w_proj, Xb);

    gemm_qkv_kernel<<<768, 256, 0, stream>>>(Xb, Wqkv, b_qkv, Qb, Kb, Vtb);

    attn_kernel<<<512, 256, 0, stream>>>(Qb, Kb, Vtb, AOb);

    gemm_proj_kernel<<<256, 256, 0, stream>>>(AOb, Wproj, b_proj, out);
}

// Round 8
// 93.641 us; speedup vs baseline: 2.3696x; 2.3696x over previous
//
#include <hip/hip_runtime.h>

#define DIM 512
#define NHEAD 8
#define HDIM 64
#define BATCH 4
#define SEQ 2048
#define MTOT (BATCH*SEQ)
#define SCALE 0.125f
#define LOG2E 1.4426950408889634f

typedef __bf16 bf16_t;
typedef __bf16 bf16x8 __attribute__((ext_vector_type(8)));
typedef __bf16 bf16x4 __attribute__((ext_vector_type(4)));
typedef float f32x4 __attribute__((ext_vector_type(4)));

#define ASYNC_COPY16(g, l) __builtin_amdgcn_global_load_lds( \
    (const __attribute__((address_space(1))) void*)(g),      \
    (__attribute__((address_space(3))) void*)(l), 16, 0, 0)

// ---------------- fused fp32 -> bf16 convert (x | w_qkv | w_proj) ----------------
#define NX_ELEM  (4194304)
#define NWQ_ELEM (786432)
#define NWP_ELEM (262144)
__global__ __launch_bounds__(256) void cvt_kernel(const float* __restrict__ x,
                                                  const float* __restrict__ wq,
                                                  const float* __restrict__ wp,
                                                  bf16_t* __restrict__ out) {
    int i = (blockIdx.x * 256 + threadIdx.x) * 4;
    const float* src;
    if (i < NX_ELEM)                 src = x  + i;
    else if (i < NX_ELEM + NWQ_ELEM) src = wq + (i - NX_ELEM);
    else                             src = wp + (i - NX_ELEM - NWQ_ELEM);
    float4 v = *reinterpret_cast<const float4*>(src);
    bf16x4 o;
    o[0] = (bf16_t)v.x; o[1] = (bf16_t)v.y; o[2] = (bf16_t)v.z; o[3] = (bf16_t)v.w;
    *reinterpret_cast<bf16x4*>(out + i) = o;
}

// ---------------- QKV GEMM: m97 structure (global_load_lds w16, linear LDS) ----------------
__global__ __launch_bounds__(256) void gemm_qkv_kernel(
    const bf16_t* __restrict__ X, const bf16_t* __restrict__ W,
    const float* __restrict__ bias,
    bf16_t* __restrict__ Qo, bf16_t* __restrict__ Ko, bf16_t* __restrict__ Vto)
{
    __shared__ bf16_t As[128][64];
    __shared__ bf16_t Bs[128][64];
    const int tid = threadIdx.x;
    const int wave = tid >> 6, lane = tid & 63;
    const int lhi = lane >> 4, llo = lane & 15;
    const int o = blockIdx.x;
    const int x = o & 7, i0 = o >> 3;
    const int m0 = (x * 8 + (i0 & 7)) * 128;
    const int n0 = (i0 >> 3) * 128;
    const int wr = (wave >> 1) * 64, wc = (wave & 1) * 64;
    f32x4 acc[4][4] = {};

    const int srow = wave * 32 + (lane >> 3);
    const int scol = (lane & 7) * 8;
    const bf16_t* gA = X + (size_t)(m0 + srow) * DIM + scol;
    const bf16_t* gB = W + (size_t)(n0 + srow) * DIM + scol;

    for (int k0 = 0; k0 < DIM; k0 += 64) {
        #pragma unroll
        for (int p = 0; p < 4; ++p) {
            ASYNC_COPY16(gA + (size_t)p * 8 * DIM + k0, &As[wave*32 + p*8][0]);
            ASYNC_COPY16(gB + (size_t)p * 8 * DIM + k0, &Bs[wave*32 + p*8][0]);
        }
        __syncthreads();
        #pragma unroll
        for (int ks = 0; ks < 2; ++ks) {
            bf16x8 af[4], bfr[4];
            #pragma unroll
            for (int i = 0; i < 4; ++i)
                af[i] = *reinterpret_cast<const bf16x8*>(&As[wr + i*16 + llo][ks*32 + lhi*8]);
            #pragma unroll
            for (int j = 0; j < 4; ++j)
                bfr[j] = *reinterpret_cast<const bf16x8*>(&Bs[wc + j*16 + llo][ks*32 + lhi*8]);
            __builtin_amdgcn_s_setprio(1);
            #pragma unroll
            for (int i = 0; i < 4; ++i)
                #pragma unroll
                for (int j = 0; j < 4; ++j)
                    acc[i][j] = __builtin_amdgcn_mfma_f32_16x16x32_bf16(af[i], bfr[j], acc[i][j], 0, 0, 0);
            __builtin_amdgcn_s_setprio(0);
        }
        __syncthreads();
    }

    #pragma unroll
    for (int j = 0; j < 4; ++j) {
        int col = n0 + wc + j*16 + llo;
        int which = col >> 9;
        int hh = (col >> 6) & 7;
        int dd = col & 63;
        float bv = bias[col];
        #pragma unroll
        for (int i = 0; i < 4; ++i) {
            #pragma unroll
            for (int r = 0; r < 4; ++r) {
                int m = m0 + wr + i*16 + lhi*4 + r;
                int b = m >> 11, ns = m & 2047;
                float v = acc[i][j][r] + bv;
                size_t bh = (size_t)(b * NHEAD + hh);
                if (which == 0)
                    Qo[(bh * SEQ + ns) * HDIM + dd] = (bf16_t)(v * (SCALE * LOG2E));
                else if (which == 1)
                    Ko[(bh * SEQ + ns) * HDIM + dd] = (bf16_t)v;
                else
                    Vto[(bh * HDIM + dd) * SEQ + ns] = (bf16_t)v;
            }
        }
    }
}

// ---------------- Flash attention v8 ----------------
// R4 structure (best measured): 8 waves x 32 q (q-tile 256), KVBLK=64, dbuf,
// 1 barrier/iter, swapped QK^T + lane-local softmax + defer-max.
// NEW: linear 128B rows + XOR swizzle (T2): elem_col ^= (row&7)*8 -> zero-
// conflict b128 reads for both K and permuted-V (single-b128 PV B-frags).
__global__ __launch_bounds__(512) void attn_kernel(
    const bf16_t* __restrict__ Q, const bf16_t* __restrict__ K,
    const bf16_t* __restrict__ Vt, bf16_t* __restrict__ O)
{
    __shared__ bf16_t Ks[2][64][64];   // [key][d], swizzled cols
    __shared__ bf16_t Vs[2][64][64];   // [d][pk], permuted + swizzled cols
    const int tid = threadIdx.x;
    const int wave = tid >> 6, lane = tid & 63;
    const int lhi = lane >> 4, llo = lane & 15;
    // XCD swizzle: 256 blocks, 32/XCD -> 4 complete bh per XCD (K/V L2-resident)
    const int o = blockIdx.x;
    const int w = (o & 7) * 32 + (o >> 3);
    const int qt = w & 7, bh = w >> 3;
    const bf16_t* Qb = Q + (size_t)bh * SEQ * HDIM;
    const bf16_t* Kb = K + (size_t)bh * SEQ * HDIM;
    const bf16_t* Vb = Vt + (size_t)bh * HDIM * SEQ;
    const int q0 = qt * 256 + wave * 32;

    // K staging: 512 thr x uint4: row ksr, 16B chunk kg
    const int ksr = tid >> 3, kg = tid & 7;
    const int kcol = (kg * 8) ^ ((ksr & 7) * 8);          // swizzled elem col
    // V staging: row vd (d), key-group vg (keys vg*8..+7), permuted pk halves
    const int vd = tid >> 3, vg = tid & 7;
    const int pkA = (32*(vg>>2) + 8*((2*vg)&3)   + 4*((vg>>1)&1)) ^ ((vd & 7) * 8);
    const int pkB = (32*(vg>>2) + 8*((2*vg+1)&3) + 4*((vg>>1)&1)) ^ ((vd & 7) * 8);

    // Q fragments (pre-scaled by SCALE*log2e); B-frag: col=llo=q, k=lhi*8+j
    bf16x8 aq[2][2];
    #pragma unroll
    for (int qb = 0; qb < 2; ++qb)
        #pragma unroll
        for (int ks = 0; ks < 2; ++ks)
            aq[qb][ks] = *reinterpret_cast<const bf16x8*>(
                Qb + (size_t)(q0 + qb*16 + llo) * HDIM + ks*32 + lhi*8);

    f32x4 acc_o[2][4] = {};          // [qb][db]: q=qb*16+lhi*4+r, d=db*16+llo
    float mstat[2], lstat[2];
    mstat[0] = mstat[1] = -1e30f;
    lstat[0] = lstat[1] = 0.f;
    const float THR = 8.0f * LOG2E;

    uint4 kreg, vreg;
    kreg = *reinterpret_cast<const uint4*>(Kb + (size_t)ksr * HDIM + kg*8);
    vreg = *reinterpret_cast<const uint4*>(Vb + (size_t)vd * SEQ + vg*8);
    *reinterpret_cast<uint4*>(&Ks[0][ksr][kcol]) = kreg;
    *reinterpret_cast<uint2*>(&Vs[0][vd][pkA]) = make_uint2(vreg.x, vreg.y);
    *reinterpret_cast<uint2*>(&Vs[0][vd][pkB]) = make_uint2(vreg.z, vreg.w);
    __syncthreads();

    const int NT = SEQ / 64;
    for (int kt = 0; kt < NT; ++kt) {
        const int cur = kt & 1, nxt = cur ^ 1;

        if (kt + 1 < NT) {   // issue next-tile loads early (hide under compute)
            const size_t koff = (size_t)(kt + 1) * 64;
            kreg = *reinterpret_cast<const uint4*>(Kb + (koff + ksr) * HDIM + kg*8);
            vreg = *reinterpret_cast<const uint4*>(Vb + (size_t)vd * SEQ + koff + vg*8);
        }

        // S^T = K Q^T: s[qb][kb], key=kb*16+lhi*4+r, q=llo
        f32x4 s[2][4] = {};
        __builtin_amdgcn_s_setprio(1);
        #pragma unroll
        for (int kb = 0; kb < 4; ++kb) {
            #pragma unroll
            for (int ks = 0; ks < 2; ++ks) {
                bf16x8 kf = *reinterpret_cast<const bf16x8*>(
                    &Ks[cur][kb*16 + llo][(ks*32 + lhi*8) ^ ((llo & 7) * 8)]);
                #pragma unroll
                for (int qb = 0; qb < 2; ++qb)
                    s[qb][kb] = __builtin_amdgcn_mfma_f32_16x16x32_bf16(kf, aq[qb][ks], s[qb][kb], 0, 0, 0);
            }
        }
        __builtin_amdgcn_s_setprio(0);

        // defer-max over lane-local 16 keys per qb
        float lmax[2];
        bool ok = true;
        #pragma unroll
        for (int qb = 0; qb < 2; ++qb) {
            float mx = s[qb][0][0];
            #pragma unroll
            for (int kb = 0; kb < 4; ++kb)
                #pragma unroll
                for (int r = 0; r < 4; ++r) mx = fmaxf(mx, s[qb][kb][r]);
            lmax[qb] = mx;
            ok &= (mx <= mstat[qb] + THR);
        }

        if (!__all(ok)) {
            #pragma unroll
            for (int qb = 0; qb < 2; ++qb) {
                float mx = lmax[qb];
                mx = fmaxf(mx, __shfl_xor(mx, 16, 64));
                mx = fmaxf(mx, __shfl_xor(mx, 32, 64));
                float mold = mstat[qb];
                float mn = fmaxf(mold, mx);
                float alpha = __builtin_amdgcn_exp2f(mold - mn);
                mstat[qb] = mn;
                lstat[qb] *= alpha;
                #pragma unroll
                for (int r = 0; r < 4; ++r) {
                    float av = __shfl(alpha, (lane & 48) >> 2 | r, 64);
                    #pragma unroll
                    for (int db = 0; db < 4; ++db) acc_o[qb][db][r] *= av;
                }
            }
        }

        // per-kp: exp + pack + PV (single swizzled b128 V reads)
        float rs[2] = {0.f, 0.f};
        #pragma unroll
        for (int kp = 0; kp < 2; ++kp) {
            bf16x8 ap[2];
            #pragma unroll
            for (int qb = 0; qb < 2; ++qb) {
                #pragma unroll
                for (int j = 0; j < 4; ++j) {
                    float p0 = __builtin_amdgcn_exp2f(s[qb][2*kp][j]     - mstat[qb]);
                    float p1 = __builtin_amdgcn_exp2f(s[qb][2*kp + 1][j] - mstat[qb]);
                    rs[qb] += p0 + p1;
                    ap[qb][j]     = (bf16_t)p0;
                    ap[qb][4 + j] = (bf16_t)p1;
                }
            }
            __builtin_amdgcn_s_setprio(1);
            #pragma unroll
            for (int db = 0; db < 4; ++db) {
                bf16x8 bv = *reinterpret_cast<const bf16x8*>(
                    &Vs[cur][db*16 + llo][(kp*32 + lhi*8) ^ ((llo & 7) * 8)]);
                #pragma unroll
                for (int qb = 0; qb < 2; ++qb)
                    acc_o[qb][db] = __builtin_amdgcn_mfma_f32_16x16x32_bf16(ap[qb], bv, acc_o[qb][db], 0, 0, 0);
            }
            __builtin_amdgcn_s_setprio(0);
        }
        #pragma unroll
        for (int qb = 0; qb < 2; ++qb) {
            float r = rs[qb];
            r += __shfl_xor(r, 16, 64);
            r += __shfl_xor(r, 32, 64);
            lstat[qb] += r;
        }

        if (kt + 1 < NT) {   // write next tile (vmcnt wait lands here)
            *reinterpret_cast<uint4*>(&Ks[nxt][ksr][kcol]) = kreg;
            *reinterpret_cast<uint2*>(&Vs[nxt][vd][pkA]) = make_uint2(vreg.x, vreg.y);
            *reinterpret_cast<uint2*>(&Vs[nxt][vd][pkB]) = make_uint2(vreg.z, vreg.w);
        }
        __syncthreads();
    }

    // normalize (stats at q=llo lanes; acc at q=lhi*4+r) + write [B,N,H*64]
    const int b = bh >> 3, h = bh & 7;
    #pragma unroll
    for (int qb = 0; qb < 2; ++qb) {
        float inv = 1.0f / lstat[qb];
        #pragma unroll
        for (int r = 0; r < 4; ++r) {
            float iv = __shfl(inv, (lane & 48) >> 2 | r, 64);
            int q = q0 + qb*16 + lhi*4 + r;
            #pragma unroll
            for (int db = 0; db < 4; ++db)
                O[(size_t)(b * SEQ + q) * DIM + h*HDIM + db*16 + llo] =
                    (bf16_t)(acc_o[qb][db][r] * iv);
        }
    }
}

// ---------------- Output proj GEMM: m97 structure ----------------
__global__ __launch_bounds__(256) void gemm_proj_kernel(
    const bf16_t* __restrict__ X, const bf16_t* __restrict__ W,
    const float* __restrict__ bias, float* __restrict__ out)
{
    __shared__ bf16_t As[128][64];
    __shared__ bf16_t Bs[128][64];
    const int tid = threadIdx.x;
    const int wave = tid >> 6, lane = tid & 63;
    const int lhi = lane >> 4, llo = lane & 15;
    const int o = blockIdx.x;
    const int x = o & 7, i0 = o >> 3;
    const int m0 = (x * 8 + (i0 & 7)) * 128;
    const int n0 = (i0 >> 3) * 128;
    const int wr = (wave >> 1) * 64, wc = (wave & 1) * 64;
    f32x4 acc[4][4] = {};

    const int srow = wave * 32 + (lane >> 3);
    const int scol = (lane & 7) * 8;
    const bf16_t* gA = X + (size_t)(m0 + srow) * DIM + scol;
    const bf16_t* gB = W + (size_t)(n0 + srow) * DIM + scol;

    for (int k0 = 0; k0 < DIM; k0 += 64) {
        #pragma unroll
        for (int p = 0; p < 4; ++p) {
            ASYNC_COPY16(gA + (size_t)p * 8 * DIM + k0, &As[wave*32 + p*8][0]);
            ASYNC_COPY16(gB + (size_t)p * 8 * DIM + k0, &Bs[wave*32 + p*8][0]);
        }
        __syncthreads();
        #pragma unroll
        for (int ks = 0; ks < 2; ++ks) {
            bf16x8 af[4], bfr[4];
            #pragma unroll
            for (int i = 0; i < 4; ++i)
                af[i] = *reinterpret_cast<const bf16x8*>(&As[wr + i*16 + llo][ks*32 + lhi*8]);
            #pragma unroll
            for (int j = 0; j < 4; ++j)
                bfr[j] = *reinterpret_cast<const bf16x8*>(&Bs[wc + j*16 + llo][ks*32 + lhi*8]);
            __builtin_amdgcn_s_setprio(1);
            #pragma unroll
            for (int i = 0; i < 4; ++i)
                #pragma unroll
                for (int j = 0; j < 4; ++j)
                    acc[i][j] = __builtin_amdgcn_mfma_f32_16x16x32_bf16(af[i], bfr[j], acc[i][j], 0, 0, 0);
            __builtin_amdgcn_s_setprio(0);
        }
        __syncthreads();
    }

    #pragma unroll
    for (int j = 0; j < 4; ++j) {
        int col = n0 + wc + j*16 + llo;
        float bv = bias[col];
        #pragma unroll
        for (int i = 0; i < 4; ++i)
            #pragma unroll
            for (int r = 0; r < 4; ++r) {
                int m = m0 + wr + i*16 + lhi*4 + r;
                out[(size_t)m * DIM + col] = acc[i][j][r] + bv;
            }
    }
}

extern "C" void kernel_launch(void* const* d_in, const int* in_sizes, int n_in,
                              void* d_out, int out_size, void* d_ws, size_t ws_size,
                              hipStream_t stream) {
    const float* x      = (const float*)d_in[0];
    const float* w_qkv  = (const float*)d_in[1];
    const float* b_qkv  = (const float*)d_in[2];
    const float* w_proj = (const float*)d_in[3];
    const float* b_proj = (const float*)d_in[4];
    float* out = (float*)d_out;

    const size_t NX  = (size_t)MTOT * DIM;
    const size_t NWQ = (size_t)3 * DIM * DIM;
    const size_t NWP = (size_t)DIM * DIM;
    const size_t NQ  = (size_t)BATCH * NHEAD * SEQ * HDIM;

    bf16_t* Xb    = (bf16_t*)d_ws;
    bf16_t* Wqkv  = Xb + NX;
    bf16_t* Wproj = Wqkv + NWQ;
    bf16_t* Qb    = Wproj + NWP;
    bf16_t* Kb    = Qb + NQ;
    bf16_t* Vtb   = Kb + NQ;
    bf16_t* AOb   = Vtb + NQ;

    cvt_kernel<<<(int)((NX + NWQ + NWP) / 1024), 256, 0, stream>>>(x, w_qkv, w_proj, Xb);

    gemm_qkv_kernel<<<768, 256, 0, stream>>>(Xb, Wqkv, b_qkv, Qb, Kb, Vtb);

    attn_kernel<<<256, 512, 0, stream>>>(Qb, Kb, Vtb, AOb);

    gemm_proj_kernel<<<256, 256, 0, stream>>>(AOb, Wproj, b_proj, out);
}